// Round 10
// baseline (178.125 us; speedup 1.0000x reference)
//
#include <hip/hip_runtime.h>
#include <cmath>

// Problem constants
#define NROWS 800        // BS*NQ
#define NCLS  81
#define MT    160        // targets
#define PPX   65536      // pixels per mask
#define SSPLIT 64        // K splits
#define CHUNK 1024       // PPX / SSPLIT
#define BK    64         // K per iteration
#define ITERS (CHUNK / BK)   // 16
#define RPB   64         // rows per block
#define RBLK  13         // ceil(800/64), rows 800..831 are pad (guarded)

// Workspace layout (bytes)
#define OFF_TBF   0
#define SZ_TBF    (MT * PPX * 2)                 // 20,971,520 (bf16, pre-swizzled)
#define OFF_CROSS (SZ_TBF)
#define OFF_SDOT  (OFF_CROSS + NROWS * MT * 4)
#define OFF_ROW   (OFF_SDOT + NROWS * MT * 4)
#define OFF_SSUM  (OFF_ROW + NROWS * 4)
#define OFF_TSUM  (OFF_SSUM + NROWS * 4)
#define OFF_PROB  (OFF_TSUM + MT * 4)
#define OFF_END   (OFF_PROB + NROWS * NCLS * 4)

typedef __attribute__((ext_vector_type(8))) short bf16x8;
typedef __attribute__((ext_vector_type(4))) float f32x4;

typedef __attribute__((address_space(3))) char lds_char;
typedef const __attribute__((address_space(1))) char glob_char;

__device__ __forceinline__ unsigned short f2bf(float f) {
    unsigned int u = __float_as_uint(f);
    unsigned int r = (u + 0x7FFFu + ((u >> 16) & 1u)) >> 16;   // RNE
    return (unsigned short)r;
}

// ---------------------------------------------------------------------------
// Kernel 1: tgt_mask fp32 -> bf16, PRE-SWIZZLED (chunk c of row m at slot
// c^(m&7)) so linear global_load_lds gives a conflict-free LDS tile. + tsum.
// ---------------------------------------------------------------------------
__global__ __launch_bounds__(256) void prep_kernel(const float* __restrict__ tgt_mask,
                                                   char* __restrict__ ws) {
    int g = blockIdx.x * 256 + threadIdx.x;
    int m = g >> 13;            // 8192 8-px chunks per row
    int kc = g & 8191;
    const float4* src = (const float4*)(tgt_mask + (size_t)m * PPX + (kc << 3));
    float4 a = src[0], b = src[1];
    float part = a.x + a.y + a.z + a.w + b.x + b.y + b.z + b.w;

    uint4 o;
    o.x = (unsigned)f2bf(a.x) | ((unsigned)f2bf(a.y) << 16);
    o.y = (unsigned)f2bf(a.z) | ((unsigned)f2bf(a.w) << 16);
    o.z = (unsigned)f2bf(b.x) | ((unsigned)f2bf(b.y) << 16);
    o.w = (unsigned)f2bf(b.z) | ((unsigned)f2bf(b.w) << 16);

    int group = kc >> 3;                 // 64-px group index
    int c = kc & 7;                      // 16B chunk within group
    int oc = (group << 3) | (c ^ (m & 7));   // swizzled chunk slot
    *(uint4*)(ws + OFF_TBF + (size_t)m * (PPX * 2) + (size_t)oc * 16) = o;

    #pragma unroll
    for (int mk = 32; mk; mk >>= 1) part += __shfl_xor(part, mk);
    __shared__ float wsum[4];
    if ((threadIdx.x & 63) == 0) wsum[threadIdx.x >> 6] = part;
    __syncthreads();
    if (threadIdx.x == 0) {
        float tot = wsum[0] + wsum[1] + wsum[2] + wsum[3];
        atomicAdd((float*)(ws + OFF_TSUM) + m, tot);
    }
}

// ---------------------------------------------------------------------------
// Kernel 2: row softmax of pred_logits -> prob[800][81]
// ---------------------------------------------------------------------------
__global__ __launch_bounds__(64) void softmax_kernel(const float* __restrict__ logits,
                                                     float* __restrict__ prob) {
    int n = blockIdx.x;
    int l = threadIdx.x;
    const float* row = logits + n * NCLS;
    float v0 = row[l];
    float v1 = (l + 64 < NCLS) ? row[l + 64] : -INFINITY;
    float mx = fmaxf(v0, v1);
    #pragma unroll
    for (int mk = 32; mk; mk >>= 1) mx = fmaxf(mx, __shfl_xor(mx, mk));
    float e0 = __expf(v0 - mx);
    float e1 = (l + 64 < NCLS) ? __expf(v1 - mx) : 0.f;
    float s = e0 + e1;
    #pragma unroll
    for (int mk = 32; mk; mk >>= 1) s += __shfl_xor(s, mk);
    float inv = 1.f / s;
    prob[n * NCLS + l] = e0 * inv;
    if (l + 64 < NCLS) prob[n * NCLS + l + 64] = e1 * inv;
}

// ---------------------------------------------------------------------------
// Kernel 3: fused elementwise + dual GEMM (split-K).
// A/B vs R8: block tile 64 rows (RPB=64) x 160 cols x 1024-px chunk -> t-chunk
// re-read traffic HALVED (512 MB -> 256 MB) at identical grid size (832 vs
// 800), waves/CU (~12) and pipeline structure. Tests the t-traffic theory.
// ---------------------------------------------------------------------------
struct XS { float4 a, b, c, d; };       // one iteration's 16 px (fp32)

__device__ __forceinline__ void loadx(XS& x, const float* xrow, int it) {
    const float* p = xrow + it * BK;
    x.a = *(const float4*)(p);
    x.b = *(const float4*)(p + 4);
    x.c = *(const float4*)(p + 8);
    x.d = *(const float4*)(p + 12);
}

// 8 px: e^v via exp2, sigmoid = t2/(1+t2), softplus accumulated in log2 units.
__device__ __forceinline__ void ew8(const float4& u, const float4& v,
                                    bf16x8& xv, bf16x8& sv,
                                    float& slog2, float& sg_acc) {
    float vals[8] = {u.x, u.y, u.z, u.w, v.x, v.y, v.z, v.w};
    #pragma unroll
    for (int j = 0; j < 8; ++j) {
        float t = vals[j];
        float vl = fminf(t * 1.44269504089f, 126.f);         // overflow clamp
        float t2 = __builtin_amdgcn_exp2f(vl);               // e^t
        float d = 1.f + t2;
        float r = __builtin_amdgcn_rcpf(d);
        float sg = t2 * r;                                   // sigmoid(t)
        slog2 += __builtin_amdgcn_logf(d);                   // log2(1+e^t)
        sg_acc += sg;
        xv[j] = (short)f2bf(t);
        sv[j] = (short)f2bf(sg);
    }
}

__global__ __launch_bounds__(256) void main_kernel(const float* __restrict__ pred_masks,
                                                   char* __restrict__ ws) {
    __shared__ __align__(16) unsigned short lds_t[MT * BK];    // 20480 B
    __shared__ __align__(16) unsigned short lds_x[RPB * BK];   //  8192 B
    __shared__ __align__(16) unsigned short lds_s[RPB * BK];   //  8192 B

    const int tid = threadIdx.x;
    const int w = tid >> 6, l = tid & 63;
    const int rb = blockIdx.x >> 6;      // 0..12
    const int s = blockIdx.x & 63;       // bid%8 = s%8 -> same-s blocks share XCD L2
    const int k_base = s * CHUNK;

    // ---- x staging coords (thread: 1 row, 16 consecutive pixels)
    const int srow = tid >> 2;           // 0..63
    const int q = tid & 3;               // quarter of the 64-px row
    const int n_glob = rb * RPB + srow;  // may be >= NROWS (pad)
    const int n_safe = n_glob < NROWS ? n_glob : NROWS - 1;
    const float* xrow = pred_masks + (size_t)n_safe * PPX + k_base + q * 16;
    const int xo0 = srow * 128 + (((2 * q + 0) ^ (srow & 7)) * 16);
    const int xo1 = srow * 128 + (((2 * q + 1) ^ (srow & 7)) * 16);

    const char* tbase = ws + OFF_TBF;

    // stage the 160x64 t-tile of k-step tt into lds_t (5 glld calls/wave)
    auto stage_t = [&](int tt) {
        const int k0 = k_base + tt * BK;
        #pragma unroll
        for (int i = 0; i < 5; ++i) {
            int rows_base = w * 40 + i * 8;
            const char* g = (const char*)tbase
                          + (size_t)(rows_base + (l >> 3)) * (PPX * 2)
                          + (size_t)k0 * 2 + (size_t)(l & 7) * 16;
            __builtin_amdgcn_global_load_lds((glob_char*)g,
                                             (lds_char*)((char*)lds_t + rows_base * 128),
                                             16, 0, 0);
        }
    };

    const int wr = w & 1, wc = w >> 1;   // wave: 32-row half x 80-col half
    const int lrow = l & 15;
    f32x4 accX[2][5], accS[2][5];
    #pragma unroll
    for (int rt = 0; rt < 2; ++rt)
        #pragma unroll
        for (int c = 0; c < 5; ++c) { accX[rt][c] = (f32x4)(0.f); accS[rt][c] = (f32x4)(0.f); }
    float slog2 = 0.f, rs_sg = 0.f;

    XS XA, XB;
    loadx(XA, xrow, 0);
    loadx(XB, xrow, 1);

    #pragma unroll 1
    for (int it = 0; it < ITERS; it += 2) {
        #pragma unroll
        for (int half = 0; half < 2; ++half) {
            const int h = it + half;
            stage_t(h);

            // elementwise on the prefetched regs, write bf16 to LDS (swizzled)
            bf16x8 xv0, sv0, xv1, sv1;
            if (half == 0) { ew8(XA.a, XA.b, xv0, sv0, slog2, rs_sg);
                             ew8(XA.c, XA.d, xv1, sv1, slog2, rs_sg); }
            else           { ew8(XB.a, XB.b, xv0, sv0, slog2, rs_sg);
                             ew8(XB.c, XB.d, xv1, sv1, slog2, rs_sg); }
            *(bf16x8*)((char*)lds_x + xo0) = xv0;
            *(bf16x8*)((char*)lds_x + xo1) = xv1;
            *(bf16x8*)((char*)lds_s + xo0) = sv0;
            *(bf16x8*)((char*)lds_s + xo1) = sv1;

            // refill the just-consumed register set, 2 tiles ahead
            int tr = h + 2; if (tr >= ITERS) tr = ITERS - 1;
            if (half == 0) loadx(XA, xrow, tr);
            else           loadx(XB, xrow, tr);

            // stage(h) retired; the 4 newer x-refill loads stay in flight
            asm volatile("s_waitcnt vmcnt(4) lgkmcnt(0)" ::: "memory");
            __builtin_amdgcn_sched_barrier(0);
            __builtin_amdgcn_s_barrier();
            __builtin_amdgcn_sched_barrier(0);

            // MFMA: per wave 32 rows x 80 cols, K=64 in two k-steps
            #pragma unroll
            for (int rt = 0; rt < 2; ++rt)
                #pragma unroll
                for (int kk = 0; kk < 2; ++kk) {
                    const int arow = wr * 32 + rt * 16 + lrow;
                    const int achunk = (kk * 4 + (l >> 4)) ^ (arow & 7);
                    bf16x8 ax = *(bf16x8*)((char*)lds_x + arow * 128 + achunk * 16);
                    bf16x8 as_ = *(bf16x8*)((char*)lds_s + arow * 128 + achunk * 16);
                    #pragma unroll
                    for (int cf = 0; cf < 5; ++cf) {
                        const int mrow = (wc * 5 + cf) * 16 + lrow;
                        const int bchunk = (kk * 4 + (l >> 4)) ^ (mrow & 7);
                        bf16x8 bv = *(bf16x8*)((char*)lds_t + mrow * 128 + bchunk * 16);
                        accX[rt][cf] = __builtin_amdgcn_mfma_f32_16x16x32_bf16(ax, bv, accX[rt][cf], 0, 0, 0);
                        accS[rt][cf] = __builtin_amdgcn_mfma_f32_16x16x32_bf16(as_, bv, accS[rt][cf], 0, 0, 0);
                    }
                }

            // LDS reads done before next half overwrites lds_* (WAR)
            asm volatile("s_waitcnt lgkmcnt(0)" ::: "memory");
            __builtin_amdgcn_sched_barrier(0);
            __builtin_amdgcn_s_barrier();
            __builtin_amdgcn_sched_barrier(0);
        }
    }

    asm volatile("s_waitcnt vmcnt(0)" ::: "memory");

    // ---- row sums: the 4 lanes sharing a row reduce, one atomic each
    float rs_sp = slog2 * 0.69314718056f;
    rs_sp += __shfl_xor(rs_sp, 1); rs_sp += __shfl_xor(rs_sp, 2);
    rs_sg += __shfl_xor(rs_sg, 1); rs_sg += __shfl_xor(rs_sg, 2);
    float* acc_row = (float*)(ws + OFF_ROW);
    float* acc_ssum = (float*)(ws + OFF_SSUM);
    if ((tid & 3) == 0 && n_glob < NROWS) {
        atomicAdd(acc_row + n_glob, rs_sp);
        atomicAdd(acc_ssum + n_glob, rs_sg);
    }

    // ---- split-K accumulate the C fragments (skip pad rows)
    float* acc_cross = (float*)(ws + OFF_CROSS);
    float* acc_sdot = (float*)(ws + OFF_SDOT);
    #pragma unroll
    for (int rt = 0; rt < 2; ++rt)
        #pragma unroll
        for (int cf = 0; cf < 5; ++cf) {
            int mcol = (wc * 5 + cf) * 16 + lrow;
            #pragma unroll
            for (int i = 0; i < 4; ++i) {
                int nrow = rb * RPB + wr * 32 + rt * 16 + (l >> 4) * 4 + i;
                if (nrow < NROWS) {
                    atomicAdd(acc_cross + nrow * MT + mcol, accX[rt][cf][i]);
                    atomicAdd(acc_sdot + nrow * MT + mcol, accS[rt][cf][i]);
                }
            }
        }
}

// ---------------------------------------------------------------------------
// Kernel 4: combine into C[n][m]
// ---------------------------------------------------------------------------
__global__ __launch_bounds__(256) void final_kernel(const int* __restrict__ tgt_ids,
                                                    const char* __restrict__ ws,
                                                    float* __restrict__ out) {
    int idx = blockIdx.x * 256 + threadIdx.x;   // 0..127999
    int n = idx / MT;
    int m = idx - n * MT;
    const float* prob = (const float*)(ws + OFF_PROB);
    const float* acc_cross = (const float*)(ws + OFF_CROSS);
    const float* acc_sdot = (const float*)(ws + OFF_SDOT);
    const float* acc_row = (const float*)(ws + OFF_ROW);
    const float* acc_ssum = (const float*)(ws + OFF_SSUM);
    const float* tsum = (const float*)(ws + OFF_TSUM);

    float cls = -prob[n * NCLS + tgt_ids[m]];
    float cmask = (acc_row[n] - acc_cross[idx]) * (1.f / PPX);
    float cdice = 1.f - (2.f * acc_sdot[idx] + 1.f) / (acc_ssum[n] + tsum[m] + 1.f);
    out[idx] = cls + cmask + cdice;
}

extern "C" void kernel_launch(void* const* d_in, const int* in_sizes, int n_in,
                              void* d_out, int out_size, void* d_ws, size_t ws_size,
                              hipStream_t stream) {
    const float* pred_logits = (const float*)d_in[0];
    const float* pred_masks  = (const float*)d_in[1];
    const int*   tgt_ids     = (const int*)d_in[2];
    const float* tgt_mask    = (const float*)d_in[3];
    char* ws = (char*)d_ws;

    (void)hipMemsetAsync(ws + OFF_CROSS, 0, OFF_END - OFF_CROSS, stream);
    prep_kernel<<<5120, 256, 0, stream>>>(tgt_mask, ws);
    softmax_kernel<<<NROWS, 64, 0, stream>>>(pred_logits, (float*)(ws + OFF_PROB));
    main_kernel<<<RBLK * SSPLIT, 256, 0, stream>>>(pred_masks, ws);
    final_kernel<<<500, 256, 0, stream>>>(tgt_ids, ws, (float*)d_out);
}

// Round 13
// 154.834 us; speedup vs baseline: 1.1504x; 1.1504x over previous
//
#include <hip/hip_runtime.h>
#include <cmath>

// Problem constants
#define NROWS 800        // BS*NQ
#define NCLS  81
#define MT    160        // targets
#define PPX   65536      // pixels per mask
#define SSPLIT 64        // K splits
#define CHUNK 1024       // PPX / SSPLIT
#define BK    64         // K per iteration
#define ITERS (CHUNK / BK)   // 16
#define RPB   32         // rows per block
#define RB    25         // row blocks (25*32 = 800 exact)

// Workspace layout (bytes)
#define OFF_TBF   0
#define SZ_TBF    (MT * PPX * 2)                 // 20,971,520 (bf16, pre-swizzled)
#define OFF_CROSS (SZ_TBF)
#define OFF_SDOT  (OFF_CROSS + NROWS * MT * 4)
#define OFF_ROW   (OFF_SDOT + NROWS * MT * 4)
#define OFF_SSUM  (OFF_ROW + NROWS * 4)
#define OFF_TSUM  (OFF_SSUM + NROWS * 4)
#define OFF_PROB  (OFF_TSUM + MT * 4)
#define OFF_END   (OFF_PROB + NROWS * NCLS * 4)

typedef __attribute__((ext_vector_type(8))) short bf16x8;
typedef __attribute__((ext_vector_type(4))) float f32x4;

typedef __attribute__((address_space(3))) char lds_char;
typedef const __attribute__((address_space(1))) char glob_char;

__device__ __forceinline__ unsigned short f2bf(float f) {
    unsigned int u = __float_as_uint(f);
    unsigned int r = (u + 0x7FFFu + ((u >> 16) & 1u)) >> 16;   // RNE
    return (unsigned short)r;
}

// ---------------------------------------------------------------------------
// Kernel 1: tgt_mask fp32 -> bf16, PRE-SWIZZLED (chunk c of row m at slot
// c^(m&7)) so linear global_load_lds gives a conflict-free LDS tile. + tsum.
// ---------------------------------------------------------------------------
__global__ __launch_bounds__(256) void prep_kernel(const float* __restrict__ tgt_mask,
                                                   char* __restrict__ ws) {
    int g = blockIdx.x * 256 + threadIdx.x;
    int m = g >> 13;            // 8192 8-px chunks per row
    int kc = g & 8191;
    const float4* src = (const float4*)(tgt_mask + (size_t)m * PPX + (kc << 3));
    float4 a = src[0], b = src[1];
    float part = a.x + a.y + a.z + a.w + b.x + b.y + b.z + b.w;

    uint4 o;
    o.x = (unsigned)f2bf(a.x) | ((unsigned)f2bf(a.y) << 16);
    o.y = (unsigned)f2bf(a.z) | ((unsigned)f2bf(a.w) << 16);
    o.z = (unsigned)f2bf(b.x) | ((unsigned)f2bf(b.y) << 16);
    o.w = (unsigned)f2bf(b.z) | ((unsigned)f2bf(b.w) << 16);

    int group = kc >> 3;                 // 64-px group index
    int c = kc & 7;                      // 16B chunk within group
    int oc = (group << 3) | (c ^ (m & 7));   // swizzled chunk slot
    *(uint4*)(ws + OFF_TBF + (size_t)m * (PPX * 2) + (size_t)oc * 16) = o;

    #pragma unroll
    for (int mk = 32; mk; mk >>= 1) part += __shfl_xor(part, mk);
    __shared__ float wsum[4];
    if ((threadIdx.x & 63) == 0) wsum[threadIdx.x >> 6] = part;
    __syncthreads();
    if (threadIdx.x == 0) {
        float tot = wsum[0] + wsum[1] + wsum[2] + wsum[3];
        atomicAdd((float*)(ws + OFF_TSUM) + m, tot);
    }
}

// ---------------------------------------------------------------------------
// Kernel 2: row softmax of pred_logits -> prob[800][81]
// ---------------------------------------------------------------------------
__global__ __launch_bounds__(64) void softmax_kernel(const float* __restrict__ logits,
                                                     float* __restrict__ prob) {
    int n = blockIdx.x;
    int l = threadIdx.x;
    const float* row = logits + n * NCLS;
    float v0 = row[l];
    float v1 = (l + 64 < NCLS) ? row[l + 64] : -INFINITY;
    float mx = fmaxf(v0, v1);
    #pragma unroll
    for (int mk = 32; mk; mk >>= 1) mx = fmaxf(mx, __shfl_xor(mx, mk));
    float e0 = __expf(v0 - mx);
    float e1 = (l + 64 < NCLS) ? __expf(v1 - mx) : 0.f;
    float s = e0 + e1;
    #pragma unroll
    for (int mk = 32; mk; mk >>= 1) s += __shfl_xor(s, mk);
    float inv = 1.f / s;
    prob[n * NCLS + l] = e0 * inv;
    if (l + 64 < NCLS) prob[n * NCLS + l + 64] = e1 * inv;
}

// ---------------------------------------------------------------------------
// Kernel 3: fused elementwise + dual GEMM (split-K).
// OCCUPANCY round (fixed): 1600 blocks (RPB=32 x SSPLIT=64) = 6.25/CU, ~5
// resident -> 20 waves/CU. Counted vmcnt(2): VALID ONLY because issue order
// is pinned -- sched_barrier(0) directly after stage_t keeps the 5 glld
// BEFORE the 2 pure x-refill loads (R11 NaN: compiler hoisted refills above
// the gllds, so vmcnt(2) left 2 gllds unretired).
// ---------------------------------------------------------------------------
struct XS { float4 a; float4 b; };      // one iteration's 8 px (fp32)

__device__ __forceinline__ void loadx(XS& x, const float* xrow, int it) {
    const float* p = xrow + it * BK;
    x.a = *(const float4*)(p);
    x.b = *(const float4*)(p + 4);
}

// 8 px: e^v via exp2, sigmoid = t2/(1+t2), softplus accumulated in log2 units.
__device__ __forceinline__ void ew8(const XS& xs, bf16x8& xv, bf16x8& sv,
                                    float& slog2, float& sg_acc) {
    float vals[8] = {xs.a.x, xs.a.y, xs.a.z, xs.a.w, xs.b.x, xs.b.y, xs.b.z, xs.b.w};
    #pragma unroll
    for (int j = 0; j < 8; ++j) {
        float v = vals[j];
        float vl = fminf(v * 1.44269504089f, 126.f);         // overflow clamp
        float t2 = __builtin_amdgcn_exp2f(vl);               // e^v
        float d = 1.f + t2;
        float r = __builtin_amdgcn_rcpf(d);
        float sg = t2 * r;                                   // sigmoid(v)
        slog2 += __builtin_amdgcn_logf(d);                   // log2(1+e^v)
        sg_acc += sg;
        xv[j] = (short)f2bf(v);
        sv[j] = (short)f2bf(sg);
    }
}

__global__ __launch_bounds__(256) void main_kernel(const float* __restrict__ pred_masks,
                                                   char* __restrict__ ws) {
    __shared__ __align__(16) unsigned short lds_t[MT * BK];    // 20480 B
    __shared__ __align__(16) unsigned short lds_x[RPB * BK];   //  4096 B
    __shared__ __align__(16) unsigned short lds_s[RPB * BK];   //  4096 B

    const int tid = threadIdx.x;
    const int w = tid >> 6, l = tid & 63;
    const int rb = blockIdx.x >> 6;      // 0..24
    const int s = blockIdx.x & 63;       // bid%8 = s%8 -> same-s blocks share XCD L2
    const int k_base = s * CHUNK;

    // ---- x staging coords (thread: 1 row, 8 consecutive pixels)
    const int srow = tid >> 3;           // 0..31
    const int sc8 = tid & 7;             // 16B chunk within 64-px row
    const int n_glob = rb * RPB + srow;
    const float* xrow = pred_masks + (size_t)n_glob * PPX + k_base + sc8 * 8;
    char* xw = (char*)lds_x + srow * 128 + ((sc8 ^ (srow & 7)) * 16);
    char* swp = (char*)lds_s + srow * 128 + ((sc8 ^ (srow & 7)) * 16);

    const char* tbase = ws + OFF_TBF;

    // stage the 160x64 t-tile of k-step tt into lds_t (5 glld calls/wave)
    auto stage_t = [&](int tt) {
        const int k0 = k_base + tt * BK;
        #pragma unroll
        for (int i = 0; i < 5; ++i) {
            int rows_base = w * 40 + i * 8;
            const char* g = (const char*)tbase
                          + (size_t)(rows_base + (l >> 3)) * (PPX * 2)
                          + (size_t)k0 * 2 + (size_t)(l & 7) * 16;
            __builtin_amdgcn_global_load_lds((glob_char*)g,
                                             (lds_char*)((char*)lds_t + rows_base * 128),
                                             16, 0, 0);
        }
    };

    const int wr = w & 1, wc = w >> 1;   // wave: 16-row half x 80-col half
    f32x4 accX[5], accS[5];
    #pragma unroll
    for (int i = 0; i < 5; ++i) { accX[i] = (f32x4)(0.f); accS[i] = (f32x4)(0.f); }
    float slog2 = 0.f, rs_sg = 0.f;

    XS XA, XB;
    loadx(XA, xrow, 0);
    loadx(XB, xrow, 1);

    #pragma unroll 1
    for (int it = 0; it < ITERS; it += 2) {
        #pragma unroll
        for (int half = 0; half < 2; ++half) {
            const int h = it + half;
            stage_t(h);
            // PIN: gllds issue before everything below (makes vmcnt(2) sound)
            __builtin_amdgcn_sched_barrier(0);

            // elementwise on the prefetched regs, write bf16 to LDS (swizzled)
            bf16x8 xv, sv;
            if (half == 0) ew8(XA, xv, sv, slog2, rs_sg);
            else           ew8(XB, xv, sv, slog2, rs_sg);
            *(bf16x8*)xw = xv;
            *(bf16x8*)swp = sv;

            // refill the just-consumed register set, 2 tiles ahead (2 loads)
            int tr = h + 2; if (tr >= ITERS) tr = ITERS - 1;
            if (half == 0) loadx(XA, xrow, tr);
            else           loadx(XB, xrow, tr);

            // queue order now provably [stage 5][refill 2]: vmcnt(2) retires
            // the stage, the 2 x-refill loads ride across the barrier.
            __builtin_amdgcn_sched_barrier(0);
            asm volatile("s_waitcnt vmcnt(2) lgkmcnt(0)" ::: "memory");
            __builtin_amdgcn_sched_barrier(0);
            __builtin_amdgcn_s_barrier();
            __builtin_amdgcn_sched_barrier(0);

            // MFMA: per wave 16 rows x 80 cols, K=64 in two k-steps
            #pragma unroll
            for (int kk = 0; kk < 2; ++kk) {
                int arow = wr * 16 + (l & 15);
                int achunk = (kk * 4 + (l >> 4)) ^ (arow & 7);
                bf16x8 ax = *(bf16x8*)((char*)lds_x + arow * 128 + achunk * 16);
                bf16x8 as_ = *(bf16x8*)((char*)lds_s + arow * 128 + achunk * 16);
                #pragma unroll
                for (int cf = 0; cf < 5; ++cf) {
                    int mrow = (wc * 5 + cf) * 16 + (l & 15);
                    int bchunk = (kk * 4 + (l >> 4)) ^ (mrow & 7);
                    bf16x8 bv = *(bf16x8*)((char*)lds_t + mrow * 128 + bchunk * 16);
                    accX[cf] = __builtin_amdgcn_mfma_f32_16x16x32_bf16(ax, bv, accX[cf], 0, 0, 0);
                    accS[cf] = __builtin_amdgcn_mfma_f32_16x16x32_bf16(as_, bv, accS[cf], 0, 0, 0);
                }
            }

            // LDS reads done before next half overwrites lds_* (WAR)
            asm volatile("s_waitcnt lgkmcnt(0)" ::: "memory");
            __builtin_amdgcn_sched_barrier(0);
            __builtin_amdgcn_s_barrier();
            __builtin_amdgcn_sched_barrier(0);
        }
    }

    asm volatile("s_waitcnt vmcnt(0)" ::: "memory");

    // ---- row sums: reduce over the 8 lanes sharing a row, one atomic each
    float rs_sp = slog2 * 0.69314718056f;
    rs_sp += __shfl_xor(rs_sp, 1); rs_sp += __shfl_xor(rs_sp, 2); rs_sp += __shfl_xor(rs_sp, 4);
    rs_sg += __shfl_xor(rs_sg, 1); rs_sg += __shfl_xor(rs_sg, 2); rs_sg += __shfl_xor(rs_sg, 4);
    float* acc_row = (float*)(ws + OFF_ROW);
    float* acc_ssum = (float*)(ws + OFF_SSUM);
    if ((tid & 7) == 0) {
        atomicAdd(acc_row + n_glob, rs_sp);
        atomicAdd(acc_ssum + n_glob, rs_sg);
    }

    // ---- split-K accumulate the C fragments
    float* acc_cross = (float*)(ws + OFF_CROSS);
    float* acc_sdot = (float*)(ws + OFF_SDOT);
    #pragma unroll
    for (int cf = 0; cf < 5; ++cf) {
        int mcol = (wc * 5 + cf) * 16 + (l & 15);
        #pragma unroll
        for (int i = 0; i < 4; ++i) {
            int nrow = rb * RPB + wr * 16 + (l >> 4) * 4 + i;
            atomicAdd(acc_cross + nrow * MT + mcol, accX[cf][i]);
            atomicAdd(acc_sdot + nrow * MT + mcol, accS[cf][i]);
        }
    }
}

// ---------------------------------------------------------------------------
// Kernel 4: combine into C[n][m]
// ---------------------------------------------------------------------------
__global__ __launch_bounds__(256) void final_kernel(const int* __restrict__ tgt_ids,
                                                    const char* __restrict__ ws,
                                                    float* __restrict__ out) {
    int idx = blockIdx.x * 256 + threadIdx.x;   // 0..127999
    int n = idx / MT;
    int m = idx - n * MT;
    const float* prob = (const float*)(ws + OFF_PROB);
    const float* acc_cross = (const float*)(ws + OFF_CROSS);
    const float* acc_sdot = (const float*)(ws + OFF_SDOT);
    const float* acc_row = (const float*)(ws + OFF_ROW);
    const float* acc_ssum = (const float*)(ws + OFF_SSUM);
    const float* tsum = (const float*)(ws + OFF_TSUM);

    float cls = -prob[n * NCLS + tgt_ids[m]];
    float cmask = (acc_row[n] - acc_cross[idx]) * (1.f / PPX);
    float cdice = 1.f - (2.f * acc_sdot[idx] + 1.f) / (acc_ssum[n] + tsum[m] + 1.f);
    out[idx] = cls + cmask + cdice;
}

extern "C" void kernel_launch(void* const* d_in, const int* in_sizes, int n_in,
                              void* d_out, int out_size, void* d_ws, size_t ws_size,
                              hipStream_t stream) {
    const float* pred_logits = (const float*)d_in[0];
    const float* pred_masks  = (const float*)d_in[1];
    const int*   tgt_ids     = (const int*)d_in[2];
    const float* tgt_mask    = (const float*)d_in[3];
    char* ws = (char*)d_ws;

    (void)hipMemsetAsync(ws + OFF_CROSS, 0, OFF_END - OFF_CROSS, stream);
    prep_kernel<<<5120, 256, 0, stream>>>(tgt_mask, ws);
    softmax_kernel<<<NROWS, 64, 0, stream>>>(pred_logits, (float*)(ws + OFF_PROB));
    main_kernel<<<RB * SSPLIT, 256, 0, stream>>>(pred_masks, ws);
    final_kernel<<<500, 256, 0, stream>>>(tgt_ids, ws, (float*)d_out);
}